// Round 12
// baseline (428.309 us; speedup 1.0000x reference)
//
#include <hip/hip_runtime.h>
#include <math.h>

// Problem constants
#define TOK   4096    // B*N
#define EDIM  512
#define HEADS 8
#define DHEAD 64
#define GCOLS 32768   // H*D*D

typedef unsigned short u16;
typedef _Float16 f16;
typedef __attribute__((ext_vector_type(8))) f16 f16x8;      // 8 fp16 = 4 VGPRs (MFMA A/B frag)
typedef __attribute__((ext_vector_type(4))) f16 f16x4;
typedef __attribute__((ext_vector_type(4))) float f32x4;    // MFMA C/D frag
typedef __attribute__((ext_vector_type(4))) unsigned short u16x4;
typedef __attribute__((ext_vector_type(8))) unsigned short u16x8;

typedef const __attribute__((address_space(1))) void* gas_ptr;
typedef __attribute__((address_space(3))) void* las_ptr;

__device__ __forceinline__ void gll16(const void* g, void* lds) {
  // async global->LDS, 16B/lane: per-lane global addr, wave-uniform LDS base,
  // lane i lands at lds + i*16
  __builtin_amdgcn_global_load_lds((gas_ptr)g, (las_ptr)lds, 16, 0, 0);
}

// Counted vmem wait: lets prefetch loads stay in flight across barriers.
#define WAITV(N) asm volatile("s_waitcnt vmcnt(" #N ")" ::: "memory")
// Raw barrier WITHOUT the implicit vmcnt(0) drain __syncthreads emits.
__device__ __forceinline__ void barrier_raw() { asm volatile("s_barrier" ::: "memory"); }

__device__ __forceinline__ u16 f2h_bits(float f) {
  union { f16 h; u16 u; } v; v.h = (f16)f;   // RNE
  return v.u;
}

// Abramowitz-Stegun 7.1.26 erf: |abs err| <= 1.5e-7, ~14 VALU insts.
__device__ __forceinline__ float fast_gelu(float x) {
  float s = x * 0.7071067811865475f;
  float ax = fabsf(s);
  float t = __builtin_amdgcn_rcpf(1.0f + 0.3275911f * ax);
  float poly = t * (0.254829592f + t * (-0.284496736f + t * (1.421413741f +
               t * (-1.453152027f + t * 1.061405429f))));
  float e = __expf(-ax * ax);
  float r = 1.0f - poly * e;
  float erfv = copysignf(r, s);
  return 0.5f * x * (1.0f + erfv);
}

// ---------------------------------------------------------------- cast x -> fp16
__global__ void cast_f16_k(const float* __restrict__ in, u16* __restrict__ out, int n) {
  int i = (blockIdx.x * blockDim.x + threadIdx.x) * 4;
  if (i + 3 < n) {
    float4 f = *(const float4*)(in + i);
    u16x4 h;
    h.x = f2h_bits(f.x); h.y = f2h_bits(f.y);
    h.z = f2h_bits(f.z); h.w = f2h_bits(f.w);
    *(u16x4*)(out + i) = h;
  }
}

// -------------------- wide transpose W[K][N] -> Wt[N][K] fp16
// 64x64 tile, 256 threads. Loads float4 (16B/lane), stores u16x8 (16B/lane).
__global__ void transpose_f16_wide_k(const float* __restrict__ in, u16* __restrict__ out,
                                     int K, int N) {
  __shared__ float tile[64][65];
  const int n0 = blockIdx.x * 64, k0 = blockIdx.y * 64;
  const int tid = threadIdx.x;   // 256
  #pragma unroll
  for (int i = 0; i < 4; i++) {
    int c = tid + i * 256;       // 1024 float4 chunks: row c>>4, col4 c&15
    int kr = c >> 4, c4 = (c & 15) * 4;
    float4 f = *(const float4*)(in + (size_t)(k0 + kr) * N + n0 + c4);
    tile[kr][c4 + 0] = f.x;
    tile[kr][c4 + 1] = f.y;
    tile[kr][c4 + 2] = f.z;
    tile[kr][c4 + 3] = f.w;
  }
  __syncthreads();
  #pragma unroll
  for (int i = 0; i < 2; i++) {
    int c = tid + i * 256;       // 512 u16x8 chunks: out-row c>>3, k-chunk c&7
    int nr = c >> 3, kc = (c & 7) * 8;
    u16x8 h;
    #pragma unroll
    for (int e = 0; e < 8; e++)
      h[e] = f2h_bits(tile[kc + e][nr]);
    *(u16x8*)(out + (size_t)(n0 + nr) * K + k0 + kc) = h;
  }
}

// merged z=3 variant for Wq/Wk/Wv (512x512 each): one launch instead of three
__global__ void transpose3_f16_k(const float* __restrict__ Wq, const float* __restrict__ Wk,
                                 const float* __restrict__ Wv, u16* __restrict__ Wqt,
                                 u16* __restrict__ Wkt, u16* __restrict__ Wvt) {
  __shared__ float tile[64][65];
  const int which = blockIdx.z;
  const float* in = which == 0 ? Wq : (which == 1 ? Wk : Wv);
  u16* out = which == 0 ? Wqt : (which == 1 ? Wkt : Wvt);
  const int n0 = blockIdx.x * 64, k0 = blockIdx.y * 64;
  const int tid = threadIdx.x;
  #pragma unroll
  for (int i = 0; i < 4; i++) {
    int c = tid + i * 256;
    int kr = c >> 4, c4 = (c & 15) * 4;
    float4 f = *(const float4*)(in + (size_t)(k0 + kr) * EDIM + n0 + c4);
    tile[kr][c4 + 0] = f.x;
    tile[kr][c4 + 1] = f.y;
    tile[kr][c4 + 2] = f.z;
    tile[kr][c4 + 3] = f.w;
  }
  __syncthreads();
  #pragma unroll
  for (int i = 0; i < 2; i++) {
    int c = tid + i * 256;
    int nr = c >> 3, kc = (c & 7) * 8;
    u16x8 h;
    #pragma unroll
    for (int e = 0; e < 8; e++)
      h[e] = f2h_bits(tile[kc + e][nr]);
    *(u16x8*)(out + (size_t)(n0 + nr) * EDIM + k0 + kc) = h;
  }
}

// ---------------------------------------------------------------- QKV GEMM
// 128x128 tile, BK=64, 4 waves (each 64x64), fp16 MFMA.
// v3 (best measured): double-buffer + prefetch + COUNTED vmcnt(8).
__global__ __launch_bounds__(256, 2) void qkv_gemm_k(
    const u16* __restrict__ xf, const u16* __restrict__ Wqt,
    const u16* __restrict__ Wkt, const u16* __restrict__ Wvt,
    const float* __restrict__ bq, const float* __restrict__ bk, const float* __restrict__ bv,
    u16* __restrict__ qho, u16* __restrict__ ko, u16* __restrict__ vTo) {
  __shared__ __align__(16) u16 As[2][16 * 512];   // 2 x 16KB
  __shared__ __align__(16) u16 Bs[2][16 * 512];   // 2 x 16KB  -> 64KB, 2 blk/CU
  const int which = blockIdx.z;
  const u16* Wt = which == 0 ? Wqt : (which == 1 ? Wkt : Wvt);
  const float* bias = which == 0 ? bq : (which == 1 ? bk : bv);
  const int m0 = blockIdx.x * 128;
  const int n0 = blockIdx.y * 128;
  const int tid = threadIdx.x;
  const int w = tid >> 6, lane = tid & 63, l15 = lane & 15, quad = lane >> 4;
  const int mhalf = w >> 1, nhalf = w & 1;

  f32x4 acc[4][4];
  #pragma unroll
  for (int i = 0; i < 4; i++)
    #pragma unroll
    for (int j = 0; j < 4; j++) acc[i][j] = f32x4{0.f, 0.f, 0.f, 0.f};

  auto stage = [&](int d, int kk) {
    #pragma unroll
    for (int i = 0; i < 8; i++) {
      int cb = w * 8 + i;
      if (cb < 16) {
        int ks = cb >> 3, mt = cb & 7;
        gll16(xf + (size_t)(m0 + mt * 16 + l15) * 512 + kk + ks * 32 + quad * 8,
              As[d] + cb * 512);
      } else {
        int bi = cb - 16, ks = bi >> 3, nt = bi & 7;
        gll16(Wt + (size_t)(n0 + nt * 16 + l15) * 512 + kk + ks * 32 + quad * 8,
              Bs[d] + bi * 512);
      }
    }
  };

  stage(0, 0);                     // 8 loads/wave in flight
  int cur = 0;
  for (int kt = 0; kt < 8; kt++) {
    if (kt < 7) { stage(cur ^ 1, (kt + 1) * 64); WAITV(8); }  // keep prefetch in flight
    else        { WAITV(0); }
    barrier_raw();                 // all waves' stage-kt data resident
    const u16* Asb = As[cur];
    const u16* Bsb = Bs[cur];
    #pragma unroll
    for (int ks = 0; ks < 2; ks++) {
      f16x8 a[4], b[4];
      #pragma unroll
      for (int mt = 0; mt < 4; mt++)
        a[mt] = *(const f16x8*)(Asb + (ks * 8 + mhalf * 4 + mt) * 512 + lane * 8);
      #pragma unroll
      for (int nt = 0; nt < 4; nt++)
        b[nt] = *(const f16x8*)(Bsb + (ks * 8 + nhalf * 4 + nt) * 512 + lane * 8);
      #pragma unroll
      for (int mt = 0; mt < 4; mt++)
        #pragma unroll
        for (int nt = 0; nt < 4; nt++)
          acc[mt][nt] = __builtin_amdgcn_mfma_f32_16x16x32_f16(a[mt], b[nt], acc[mt][nt], 0, 0, 0);
    }
    barrier_raw();                 // protect buf[cur] before next iter's stage()
    cur ^= 1;
  }
  #pragma unroll
  for (int nt = 0; nt < 4; nt++) {
    int col = n0 + (nhalf * 4 + nt) * 16 + l15;
    float bia = bias[col];
    int h = col >> 6, d = col & 63;
    #pragma unroll
    for (int mt = 0; mt < 4; mt++) {
      #pragma unroll
      for (int r = 0; r < 4; r++) {
        int t = m0 + (mhalf * 4 + mt) * 16 + quad * 4 + r;
        int b_ = t >> 10, n = t & 1023;
        float val = acc[mt][nt][r] + bia;
        size_t idx = (((size_t)(b_ * 8 + h) * 1024) + n) * 64 + d;
        if (which == 0)      qho[idx] = f2h_bits(val);
        else if (which == 1) ko[idx] = f2h_bits(val);
        else                 vTo[(((size_t)(b_ * 8 + h) * 64) + d) * 1024 + n] = f2h_bits(val);
      }
    }
  }
}

// ---------------------------------------------------------------- fused g-GEMM + q.g
// v12: byte-reduction. Cross-round regression (v3 6MB/CU->280us, v6 8MB->306,
// v5 12MB->407) shows qg is STAGING-BYTE-BOUND at ~9-11 B/cyc/CU global->LDS
// service (m13's rate). B-staging scales 1/M-tokens; doubling M to 256 cuts
// total staged bytes 1.54GB -> 1.05GB (-32%). Block = 256 tok x head x
// jp-half: 1024 thr (16 waves, 4/SIMD), 8 jp x 8 kk = 64 stages of
// (A 32K + B 32K), v3's exact schedule (issue-before-WAITV(4), two raw
// barriers -- also halves barrier count). Per-wave registers identical to v3
// (zacc[4][4]+qg[4], ~108 VGPR -- no spill). LDS 152KB, 1 blk/CU. Output:
// 2 fp32 d-half partials summed in attn (R9-verified pattern).
__global__ __launch_bounds__(1024, 1) void qg_fused_k(
    const u16* __restrict__ xf, const u16* __restrict__ Wgt,
    const float* __restrict__ bg, const u16* __restrict__ qh,
    float* __restrict__ qgp) {
  __shared__ __align__(16) u16 As[2][32 * 512];   // 2 x 32KB: 256 tok x 64 K
  __shared__ __align__(16) u16 Bs[2][32 * 512];   // 2 x 32KB: 256 cols x 64 K
  __shared__ __align__(16) u16 Qs[256 * 32];      // 16KB: q fp16, this d-half
  __shared__ __align__(16) float bgs[2048];       // 8KB: bg, this (head,jh)
  const int head = blockIdx.x & 7;                // XCD-pinned per head
  const int jh = (blockIdx.x >> 3) & 1;           // d-half (32 d's, 2048 cols)
  const int t0 = (blockIdx.x >> 4) * 256;         // 16 t-tiles
  const int tid = threadIdx.x;
  const int w = tid >> 6, lane = tid & 63, l15 = lane & 15, quad = lane >> 4;
  const int mq = w >> 2;      // 0..3  (64-row quarter)
  const int ntA = w & 3;      // 0..3  (16-col e-tile)
  const int b_ = t0 >> 10, nseq0 = t0 & 1023;
  const int bh = b_ * 8 + head;
  const u16* qbase = qh + (((size_t)bh * 1024) + nseq0) * 64;
  const float* bgbase = bg + head * 4096 + jh * 2048;

  // prologue (uniform 2 loads/wave): Qs = 16 chunks (1/wave); bgs = 8 chunks,
  // waves w and w+8 load the same chunk (same src+dest -> benign).
  gll16(qbase + (size_t)(w * 16 + (lane >> 2)) * 64 + jh * 32 + (lane & 3) * 8,
        Qs + w * 512);
  gll16(bgbase + (size_t)(w & 7) * 256 + (size_t)lane * 4, bgs + (w & 7) * 256);

  // Per stage: A 32 blocks (2/wave) + B 32 blocks (2/wave) = 4 gll16/wave.
  auto stage = [&](int d, int s) {
    int jp = s >> 3, kk = (s & 7) << 6;
    const u16* bsrc = Wgt + (size_t)(head * 4096 + jh * 2048 + jp * 256) * 512;
    #pragma unroll
    for (int i = 0; i < 2; i++) {
      int cb = w * 2 + i, ks = cb >> 4, mt = cb & 15;
      gll16(xf + (size_t)(t0 + mt * 16 + l15) * 512 + kk + ks * 32 + quad * 8,
            As[d] + cb * 512);
    }
    #pragma unroll
    for (int i = 0; i < 2; i++) {
      int bi = w * 2 + i, ks = bi >> 4, nt = bi & 15;
      gll16(bsrc + (size_t)(nt * 16 + l15) * 512 + kk + ks * 32 + quad * 8,
            Bs[d] + bi * 512);
    }
  };

  f32x4 qg[4];
  #pragma unroll
  for (int i = 0; i < 4; i++) qg[i] = f32x4{0.f, 0.f, 0.f, 0.f};
  f32x4 zacc[4][4];                               // [mt][z]: z = d-offset 0..3
  #pragma unroll
  for (int i = 0; i < 4; i++)
    #pragma unroll
    for (int z = 0; z < 4; z++) zacc[i][z] = f32x4{0.f, 0.f, 0.f, 0.f};

  stage(0, 0);                     // 4 loads/wave in flight (+2 prologue)
  int cur = 0;
  for (int s = 0; s < 64; s++) {
    if (s < 63) { stage(cur ^ 1, s + 1); WAITV(4); }  // stage-s done, prefetch flying
    else        { WAITV(0); }
    barrier_raw();                 // all waves' stage-s data resident
    const u16* Asb = As[cur];
    const u16* Bsb = Bs[cur];
    #pragma unroll
    for (int ks = 0; ks < 2; ks++) {
      f16x8 a[4];
      #pragma unroll
      for (int mt = 0; mt < 4; mt++)
        a[mt] = *(const f16x8*)(Asb + (ks * 16 + mq * 4 + mt) * 512 + lane * 8);
      #pragma unroll
      for (int z = 0; z < 4; z++) {
        int nt = (z >> 1) * 8 + (z & 1) * 4 + ntA;
        f16x8 b = *(const f16x8*)(Bsb + (ks * 16 + nt) * 512 + lane * 8);
        #pragma unroll
        for (int mt = 0; mt < 4; mt++)
          zacc[mt][z] = __builtin_amdgcn_mfma_f32_16x16x32_f16(a[mt], b, zacc[mt][z], 0, 0, 0);
      }
    }
    if ((s & 7) == 7) {
      // epilogue for j-group jp: d_local = jp*4 + z (global d = jh*32 + ...).
      // bias (LDS f32) + gelu + contract with fp16 q; overlaps prefetch.
      int jp = s >> 3;
      float bgv[4];
      #pragma unroll
      for (int z = 0; z < 4; z++) {
        int nt = (z >> 1) * 8 + (z & 1) * 4 + ntA;
        bgv[z] = bgs[jp * 256 + nt * 16 + l15];
      }
      const int d0 = jp * 4;
      #pragma unroll
      for (int mt = 0; mt < 4; mt++) {
        #pragma unroll
        for (int r = 0; r < 4; r++) {
          int row = mq * 64 + mt * 16 + quad * 4 + r;
          f16x4 qp = *(const f16x4*)(Qs + row * 32 + d0);  // q[row][d0..d0+3]
          float g0 = fast_gelu(zacc[mt][0][r] + bgv[0]);
          float g1 = fast_gelu(zacc[mt][1][r] + bgv[1]);
          float g2 = fast_gelu(zacc[mt][2][r] + bgv[2]);
          float g3 = fast_gelu(zacc[mt][3][r] + bgv[3]);
          qg[mt][r] += (float)qp.x * g0 + (float)qp.y * g1 +
                       (float)qp.z * g2 + (float)qp.w * g3;
        }
      }
      #pragma unroll
      for (int i = 0; i < 4; i++)
        #pragma unroll
        for (int z = 0; z < 4; z++) zacc[i][z] = f32x4{0.f, 0.f, 0.f, 0.f};
    }
    barrier_raw();                 // protect buf[cur] before next iter's stage()
    cur ^= 1;
  }
  // write fp32 d-half partial [jh][B*H][N][D]
  float* outp = qgp + (size_t)jh * TOK * 512 + ((size_t)bh * 1024) * 64;
  const int eb = ntA * 16;
  #pragma unroll
  for (int mt = 0; mt < 4; mt++) {
    #pragma unroll
    for (int r = 0; r < 4; r++) {
      int tok = mq * 64 + mt * 16 + quad * 4 + r;
      int n = nseq0 + tok;
      outp[(size_t)n * 64 + eb + l15] = qg[mt][r];
    }
  }
}

// ---------------------------------------------------------------- flash attention
// Block = (b,h,qtile64), 4 waves x 16 q-rows. qg = sum of 2 fp32 d-half
// partials (one-time per block); counted vmcnt(4) + raw barriers. (R9-exact.)
__global__ __launch_bounds__(256, 2) void attn_k(
    const float* __restrict__ qgp, const u16* __restrict__ kb,
    const u16* __restrict__ vTb, float* __restrict__ out) {
  __shared__ __align__(16) u16 Ks[2][8 * 512];
  __shared__ __align__(16) u16 Vs[2][8 * 512];
  __shared__ __align__(16) f16 Ps[4][16 * 72];    // per-wave P, row stride 72
  const int idx = blockIdx.x;
  const int bh = idx & 31;   // b*8+h -> XCD = bh%8
  const int qt = idx >> 5;
  const int b_ = bh >> 3, h = bh & 7;
  const int tid = threadIdx.x;
  const int w = tid >> 6, lane = tid & 63, l15 = lane & 15, quad = lane >> 4;

  const float* qg0 = qgp + ((size_t)bh * 1024) * 64;
  const float* qg1 = qg0 + (size_t)TOK * 512;     // partial stride = 2M elems
  const u16* kB  = kb  + (size_t)bh * 1024 * 64;
  const u16* vB  = vTb + (size_t)bh * 64 * 1024;

  f16x8 aq[2];
  #pragma unroll
  for (int ks = 0; ks < 2; ks++) {
    size_t off = (size_t)(qt * 64 + w * 16 + l15) * 64 + ks * 32 + quad * 8;
    f16x8 v;
    #pragma unroll
    for (int e = 0; e < 8; e++)
      v[e] = (f16)(qg0[off + e] + qg1[off + e]);
    aq[ks] = v;
  }

  f32x4 o[4];
  #pragma unroll
  for (int i = 0; i < 4; i++) o[i] = f32x4{0.f, 0.f, 0.f, 0.f};
  float m_old[4], l_old[4];
  #pragma unroll
  for (int r = 0; r < 4; r++) { m_old[r] = -1e30f; l_old[r] = 0.f; }

  auto stageKV = [&](int d, int kt) {
    #pragma unroll
    for (int i = 0; i < 2; i++) {
      int cb = w * 2 + i;
      int ks = cb >> 2, nt = cb & 3;
      gll16(kB + (size_t)(kt * 64 + nt * 16 + l15) * 64 + ks * 32 + quad * 8, Ks[d] + cb * 512);
      gll16(vB + (size_t)(nt * 16 + l15) * 1024 + kt * 64 + ks * 32 + quad * 8, Vs[d] + cb * 512);
    }
  };

  stageKV(0, 0);                   // 4 loads/wave in flight
  int cur = 0;
  for (int kt = 0; kt < 16; kt++) {
    if (kt < 15) { stageKV(cur ^ 1, kt + 1); WAITV(4); }
    else         { WAITV(0); }
    barrier_raw();
    f32x4 s[4];
    #pragma unroll
    for (int nt = 0; nt < 4; nt++) s[nt] = f32x4{0.f, 0.f, 0.f, 0.f};
    #pragma unroll
    for (int ks = 0; ks < 2; ks++)
      #pragma unroll
      for (int nt = 0; nt < 4; nt++) {
        f16x8 kf = *(const f16x8*)(Ks[cur] + (ks * 4 + nt) * 512 + lane * 8);
        s[nt] = __builtin_amdgcn_mfma_f32_16x16x32_f16(aq[ks], kf, s[nt], 0, 0, 0);
      }
    float rmax[4];
    #pragma unroll
    for (int r = 0; r < 4; r++)
      rmax[r] = fmaxf(fmaxf(s[0][r], s[1][r]), fmaxf(s[2][r], s[3][r]));
    #pragma unroll
    for (int off = 1; off < 16; off <<= 1)
      #pragma unroll
      for (int r = 0; r < 4; r++)
        rmax[r] = fmaxf(rmax[r], __shfl_xor(rmax[r], off));
    float alpha[4], rsum[4];
    #pragma unroll
    for (int r = 0; r < 4; r++) {
      float mn = fmaxf(m_old[r], rmax[r]);
      alpha[r] = __expf(m_old[r] - mn);
      m_old[r] = mn;
      rsum[r] = 0.f;
    }
    #pragma unroll
    for (int nt = 0; nt < 4; nt++)
      #pragma unroll
      for (int r = 0; r < 4; r++) {
        float p = __expf(s[nt][r] - m_old[r]);
        rsum[r] += p;
        Ps[w][(quad * 4 + r) * 72 + nt * 16 + l15] = (f16)p;
      }
    #pragma unroll
    for (int off = 1; off < 16; off <<= 1)
      #pragma unroll
      for (int r = 0; r < 4; r++)
        rsum[r] += __shfl_xor(rsum[r], off);
    #pragma unroll
    for (int r = 0; r < 4; r++) l_old[r] = l_old[r] * alpha[r] + rsum[r];
    #pragma unroll
    for (int nt = 0; nt < 4; nt++)
      #pragma unroll
      for (int r = 0; r < 4; r++) o[nt][r] *= alpha[r];
    #pragma unroll
    for (int ks = 0; ks < 2; ks++) {
      f16x8 pa = *(const f16x8*)(&Ps[w][l15 * 72 + ks * 32 + quad * 8]);
      #pragma unroll
      for (int nt = 0; nt < 4; nt++) {
        f16x8 vf = *(const f16x8*)(Vs[cur] + (ks * 4 + nt) * 512 + lane * 8);
        o[nt] = __builtin_amdgcn_mfma_f32_16x16x32_f16(pa, vf, o[nt], 0, 0, 0);
      }
    }
    barrier_raw();                 // protect Ks/Vs[cur] before next stageKV
    cur ^= 1;
  }
  #pragma unroll
  for (int r = 0; r < 4; r++) {
    float inv = 1.f / l_old[r];
    int n = qt * 64 + w * 16 + quad * 4 + r;
    #pragma unroll
    for (int nt = 0; nt < 4; nt++)
      out[((size_t)(b_ * 1024 + n)) * 512 + h * 64 + nt * 16 + l15] = o[nt][r] * inv;
  }
}

// ----------------------------------------------------------------------- host
extern "C" void kernel_launch(void* const* d_in, const int* in_sizes, int n_in,
                              void* d_out, int out_size, void* d_ws, size_t ws_size,
                              hipStream_t stream) {
  const float* x  = (const float*)d_in[0];
  const float* Wq = (const float*)d_in[1];
  const float* bq = (const float*)d_in[2];
  const float* Wk = (const float*)d_in[3];
  const float* bk = (const float*)d_in[4];
  const float* Wv = (const float*)d_in[5];
  const float* bv = (const float*)d_in[6];
  const float* Wg = (const float*)d_in[7];
  const float* bg = (const float*)d_in[8];
  float* out = (float*)d_out;

  const size_t NX = (size_t)TOK * EDIM;        // 2M elems
  const size_t NWG = (size_t)GCOLS * EDIM;     // 16.8M elems
  const size_t NW = (size_t)EDIM * EDIM;       // 256K elems

  char* p = (char*)d_ws;
  u16* xf  = (u16*)p; p += NX * 2;             // x fp16
  u16* Wgt = (u16*)p; p += NWG * 2;            // Wg^T fp16 (33.5 MB)
  u16* Wqt = (u16*)p; p += NW * 2;
  u16* Wkt = (u16*)p; p += NW * 2;
  u16* Wvt = (u16*)p; p += NW * 2;
  u16* qh  = (u16*)p; p += NX * 2;             // q fp16 [B][H][N][D]
  u16* kf  = (u16*)p; p += NX * 2;             // k fp16
  u16* vT  = (u16*)p; p += NX * 2;             // v^T fp16
  float* qgp = (float*)p; p += NX * 4 * 2;     // qg fp32 partials [2][B*H][N][D] (16MB)

  hipLaunchKernelGGL(cast_f16_k, dim3(NX / 1024), dim3(256), 0, stream,
                     x, xf, (int)NX);
  hipLaunchKernelGGL(transpose3_f16_k, dim3(EDIM / 64, EDIM / 64, 3), dim3(256), 0, stream,
                     Wq, Wk, Wv, Wqt, Wkt, Wvt);
  hipLaunchKernelGGL(transpose_f16_wide_k, dim3(GCOLS / 64, EDIM / 64), dim3(256), 0, stream,
                     Wg, Wgt, EDIM, GCOLS);
  hipLaunchKernelGGL(qkv_gemm_k, dim3(TOK / 128, EDIM / 128, 3), dim3(256), 0, stream,
                     xf, Wqt, Wkt, Wvt, bq, bk, bv, qh, kf, vT);
  hipLaunchKernelGGL(qg_fused_k, dim3(256), dim3(1024), 0, stream,
                     xf, Wgt, bg, qh, qgp);
  hipLaunchKernelGGL(attn_k, dim3(512), dim3(256), 0, stream,
                     qgp, kf, vT, out);
}

// Round 13
// 422.374 us; speedup vs baseline: 1.0141x; 1.0141x over previous
//
#include <hip/hip_runtime.h>
#include <math.h>

// Problem constants
#define TOK   4096    // B*N
#define EDIM  512
#define HEADS 8
#define DHEAD 64
#define GCOLS 32768   // H*D*D

typedef unsigned short u16;
typedef _Float16 f16;
typedef __attribute__((ext_vector_type(8))) f16 f16x8;      // 8 fp16 = 4 VGPRs (MFMA A/B frag)
typedef __attribute__((ext_vector_type(4))) f16 f16x4;
typedef __attribute__((ext_vector_type(4))) float f32x4;    // MFMA C/D frag
typedef __attribute__((ext_vector_type(4))) unsigned short u16x4;
typedef __attribute__((ext_vector_type(8))) unsigned short u16x8;

typedef const __attribute__((address_space(1))) void* gas_ptr;
typedef __attribute__((address_space(3))) void* las_ptr;

__device__ __forceinline__ void gll16(const void* g, void* lds) {
  // async global->LDS, 16B/lane: per-lane global addr, wave-uniform LDS base,
  // lane i lands at lds + i*16
  __builtin_amdgcn_global_load_lds((gas_ptr)g, (las_ptr)lds, 16, 0, 0);
}

// Counted vmem wait: lets prefetch loads stay in flight across barriers.
#define WAITV(N) asm volatile("s_waitcnt vmcnt(" #N ")" ::: "memory")
// Raw barrier WITHOUT the implicit vmcnt(0) drain __syncthreads emits.
__device__ __forceinline__ void barrier_raw() { asm volatile("s_barrier" ::: "memory"); }

__device__ __forceinline__ u16 f2h_bits(float f) {
  union { f16 h; u16 u; } v; v.h = (f16)f;   // RNE
  return v.u;
}

// Abramowitz-Stegun 7.1.26 erf: |abs err| <= 1.5e-7, ~14 VALU insts.
__device__ __forceinline__ float fast_gelu(float x) {
  float s = x * 0.7071067811865475f;
  float ax = fabsf(s);
  float t = __builtin_amdgcn_rcpf(1.0f + 0.3275911f * ax);
  float poly = t * (0.254829592f + t * (-0.284496736f + t * (1.421413741f +
               t * (-1.453152027f + t * 1.061405429f))));
  float e = __expf(-ax * ax);
  float r = 1.0f - poly * e;
  float erfv = copysignf(r, s);
  return 0.5f * x * (1.0f + erfv);
}

// ---------------------------------------------------------------- cast x -> fp16
__global__ void cast_f16_k(const float* __restrict__ in, u16* __restrict__ out, int n) {
  int i = (blockIdx.x * blockDim.x + threadIdx.x) * 4;
  if (i + 3 < n) {
    float4 f = *(const float4*)(in + i);
    u16x4 h;
    h.x = f2h_bits(f.x); h.y = f2h_bits(f.y);
    h.z = f2h_bits(f.z); h.w = f2h_bits(f.w);
    *(u16x4*)(out + i) = h;
  }
}

// -------------------- wide transpose W[K][N] -> Wt[N][K] fp16
// 64x64 tile, 256 threads. Loads float4 (16B/lane), stores u16x8 (16B/lane).
// LDS f32 tile padded to 65: bank = (k*65+n)%32 = (k+n)%32 -> conflict-free
// on row writes; column reads hit each bank exactly 2x (free, m136).
__global__ void transpose_f16_wide_k(const float* __restrict__ in, u16* __restrict__ out,
                                     int K, int N) {
  __shared__ float tile[64][65];
  const int n0 = blockIdx.x * 64, k0 = blockIdx.y * 64;
  const int tid = threadIdx.x;   // 256
  #pragma unroll
  for (int i = 0; i < 4; i++) {
    int c = tid + i * 256;       // 1024 float4 chunks: row c>>4, col4 c&15
    int kr = c >> 4, c4 = (c & 15) * 4;
    float4 f = *(const float4*)(in + (size_t)(k0 + kr) * N + n0 + c4);
    tile[kr][c4 + 0] = f.x;
    tile[kr][c4 + 1] = f.y;
    tile[kr][c4 + 2] = f.z;
    tile[kr][c4 + 3] = f.w;
  }
  __syncthreads();
  #pragma unroll
  for (int i = 0; i < 2; i++) {
    int c = tid + i * 256;       // 512 u16x8 chunks: out-row c>>3, k-chunk c&7
    int nr = c >> 3, kc = (c & 7) * 8;
    u16x8 h;
    #pragma unroll
    for (int e = 0; e < 8; e++)
      h[e] = f2h_bits(tile[kc + e][nr]);
    *(u16x8*)(out + (size_t)(n0 + nr) * K + k0 + kc) = h;
  }
}

// merged z=3 variant for Wq/Wk/Wv (512x512 each): one launch instead of three
__global__ void transpose3_f16_k(const float* __restrict__ Wq, const float* __restrict__ Wk,
                                 const float* __restrict__ Wv, u16* __restrict__ Wqt,
                                 u16* __restrict__ Wkt, u16* __restrict__ Wvt) {
  __shared__ float tile[64][65];
  const int which = blockIdx.z;
  const float* in = which == 0 ? Wq : (which == 1 ? Wk : Wv);
  u16* out = which == 0 ? Wqt : (which == 1 ? Wkt : Wvt);
  const int n0 = blockIdx.x * 64, k0 = blockIdx.y * 64;
  const int tid = threadIdx.x;
  #pragma unroll
  for (int i = 0; i < 4; i++) {
    int c = tid + i * 256;
    int kr = c >> 4, c4 = (c & 15) * 4;
    float4 f = *(const float4*)(in + (size_t)(k0 + kr) * EDIM + n0 + c4);
    tile[kr][c4 + 0] = f.x;
    tile[kr][c4 + 1] = f.y;
    tile[kr][c4 + 2] = f.z;
    tile[kr][c4 + 3] = f.w;
  }
  __syncthreads();
  #pragma unroll
  for (int i = 0; i < 2; i++) {
    int c = tid + i * 256;
    int nr = c >> 3, kc = (c & 7) * 8;
    u16x8 h;
    #pragma unroll
    for (int e = 0; e < 8; e++)
      h[e] = f2h_bits(tile[kc + e][nr]);
    *(u16x8*)(out + (size_t)(n0 + nr) * EDIM + k0 + kc) = h;
  }
}

// ---------------------------------------------------------------- QKV GEMM
// 128x128 tile, BK=64, 4 waves (each 64x64), fp16 MFMA.
// v3 (best measured): double-buffer + prefetch + COUNTED vmcnt(8)
// with raw s_barrier -- prefetch stays in flight across both barriers.
__global__ __launch_bounds__(256, 2) void qkv_gemm_k(
    const u16* __restrict__ xf, const u16* __restrict__ Wqt,
    const u16* __restrict__ Wkt, const u16* __restrict__ Wvt,
    const float* __restrict__ bq, const float* __restrict__ bk, const float* __restrict__ bv,
    u16* __restrict__ qho, u16* __restrict__ ko, u16* __restrict__ vTo) {
  __shared__ __align__(16) u16 As[2][16 * 512];   // 2 x 16KB
  __shared__ __align__(16) u16 Bs[2][16 * 512];   // 2 x 16KB  -> 64KB, 2 blk/CU
  const int which = blockIdx.z;
  const u16* Wt = which == 0 ? Wqt : (which == 1 ? Wkt : Wvt);
  const float* bias = which == 0 ? bq : (which == 1 ? bk : bv);
  const int m0 = blockIdx.x * 128;
  const int n0 = blockIdx.y * 128;
  const int tid = threadIdx.x;
  const int w = tid >> 6, lane = tid & 63, l15 = lane & 15, quad = lane >> 4;
  const int mhalf = w >> 1, nhalf = w & 1;

  f32x4 acc[4][4];
  #pragma unroll
  for (int i = 0; i < 4; i++)
    #pragma unroll
    for (int j = 0; j < 4; j++) acc[i][j] = f32x4{0.f, 0.f, 0.f, 0.f};

  auto stage = [&](int d, int kk) {
    #pragma unroll
    for (int i = 0; i < 8; i++) {
      int cb = w * 8 + i;
      if (cb < 16) {
        int ks = cb >> 3, mt = cb & 7;
        gll16(xf + (size_t)(m0 + mt * 16 + l15) * 512 + kk + ks * 32 + quad * 8,
              As[d] + cb * 512);
      } else {
        int bi = cb - 16, ks = bi >> 3, nt = bi & 7;
        gll16(Wt + (size_t)(n0 + nt * 16 + l15) * 512 + kk + ks * 32 + quad * 8,
              Bs[d] + bi * 512);
      }
    }
  };

  stage(0, 0);                     // 8 loads/wave in flight
  int cur = 0;
  for (int kt = 0; kt < 8; kt++) {
    if (kt < 7) { stage(cur ^ 1, (kt + 1) * 64); WAITV(8); }  // keep prefetch in flight
    else        { WAITV(0); }
    barrier_raw();                 // all waves' stage-kt data resident
    const u16* Asb = As[cur];
    const u16* Bsb = Bs[cur];
    #pragma unroll
    for (int ks = 0; ks < 2; ks++) {
      f16x8 a[4], b[4];
      #pragma unroll
      for (int mt = 0; mt < 4; mt++)
        a[mt] = *(const f16x8*)(Asb + (ks * 8 + mhalf * 4 + mt) * 512 + lane * 8);
      #pragma unroll
      for (int nt = 0; nt < 4; nt++)
        b[nt] = *(const f16x8*)(Bsb + (ks * 8 + nhalf * 4 + nt) * 512 + lane * 8);
      #pragma unroll
      for (int mt = 0; mt < 4; mt++)
        #pragma unroll
        for (int nt = 0; nt < 4; nt++)
          acc[mt][nt] = __builtin_amdgcn_mfma_f32_16x16x32_f16(a[mt], b[nt], acc[mt][nt], 0, 0, 0);
    }
    barrier_raw();                 // protect buf[cur] before next iter's stage()
    cur ^= 1;
  }
  #pragma unroll
  for (int nt = 0; nt < 4; nt++) {
    int col = n0 + (nhalf * 4 + nt) * 16 + l15;
    float bia = bias[col];
    int h = col >> 6, d = col & 63;
    #pragma unroll
    for (int mt = 0; mt < 4; mt++) {
      #pragma unroll
      for (int r = 0; r < 4; r++) {
        int t = m0 + (mhalf * 4 + mt) * 16 + quad * 4 + r;
        int b_ = t >> 10, n = t & 1023;
        float val = acc[mt][nt][r] + bia;
        size_t idx = (((size_t)(b_ * 8 + h) * 1024) + n) * 64 + d;
        if (which == 0)      qho[idx] = f2h_bits(val);
        else if (which == 1) ko[idx] = f2h_bits(val);
        else                 vTo[(((size_t)(b_ * 8 + h) * 64) + d) * 1024 + n] = f2h_bits(val);
      }
    }
  }
}

// ---------------------------------------------------------------- fused g-GEMM + q.g
// v3 (best measured 279us/dispatch): 128 tok x head x full d, 16 jp x 8 kk
// = 128 stages, dbuf As/Bs, issue-before-WAITV(6), two raw barriers; bg
// staged to LDS so the epilogue issues no global loads; fp16 qg16 output.
// Twelve rounds of structural variants (counted-vmcnt depth, triple-buffer,
// tile/occupancy changes 22-47%, staged-bytes 4-12MB/CU, m97-drain at 2-4
// blk/CU, hoisted addressing, M=256 byte-halving) all measured >= this form:
// the ~80-reg accumulator state pins it to 2 waves/SIMD, and the per-stage
// window self-consistently equals the global->LDS service time of one tile.
__global__ __launch_bounds__(512, 2) void qg_fused_k(
    const u16* __restrict__ xf, const u16* __restrict__ Wgt,
    const float* __restrict__ bg, const u16* __restrict__ qh,
    u16* __restrict__ qg16) {
  __shared__ __align__(16) u16 As[2][16 * 512];   // 2 x 16KB: 128 tok x 64 K
  __shared__ __align__(16) u16 Bs[2][32 * 512];   // 2 x 32KB: 256 cols x 64 K
  __shared__ __align__(16) u16 Qs[128 * 64];      // 16KB: q fp16 rows
  __shared__ __align__(16) float bgs[4096];       // 16KB: bg head slice
  const int head = blockIdx.x & 7;                // XCD-pinned per head
  const int t0 = (blockIdx.x >> 3) * 128;
  const int tid = threadIdx.x;
  const int w = tid >> 6, lane = tid & 63, l15 = lane & 15, quad = lane >> 4;
  const int mhalf = w >> 2;   // 0..1  (token half)
  const int ntA = w & 3;      // 0..3  (e-range /16)
  const int b_ = t0 >> 10, nseq0 = t0 & 1023;
  const u16* qbase = qh + (((size_t)(b_ * 8 + head) * 1024) + nseq0) * 64;
  const float* bgbase = bg + head * 4096;

  // stage Qs (16KB fp16) + bgs (16KB f32); drained by the first WAITV(6)
  #pragma unroll
  for (int i = 0; i < 2; i++) {
    int cb = w * 2 + i;
    gll16(qbase + (size_t)cb * 512 + (size_t)lane * 8, Qs + (size_t)cb * 512);
    gll16(bgbase + (size_t)cb * 256 + (size_t)lane * 4, bgs + (size_t)cb * 256);
  }

  auto stage = [&](int d, int s) {
    int jp = s >> 3, kk = (s & 7) << 6;
    int c0 = head * 4096 + jp * 256;              // 256 contiguous cols (4 d's)
    #pragma unroll
    for (int i = 0; i < 6; i++) {
      int cb = w * 6 + i;
      if (cb < 16) {
        int ks = cb >> 3, mt = cb & 7;
        gll16(xf + (size_t)(t0 + mt * 16 + l15) * 512 + kk + ks * 32 + quad * 8,
              As[d] + cb * 512);
      } else {
        int bi = cb - 16, ks = bi >> 4, nt = bi & 15;
        gll16(Wgt + (size_t)(c0 + nt * 16 + l15) * 512 + kk + ks * 32 + quad * 8,
              Bs[d] + bi * 512);
      }
    }
  };

  f32x4 qg[4];
  #pragma unroll
  for (int i = 0; i < 4; i++) qg[i] = f32x4{0.f, 0.f, 0.f, 0.f};
  f32x4 zacc[4][4];                               // [mt][z]: z = d-offset 0..3
  #pragma unroll
  for (int i = 0; i < 4; i++)
    #pragma unroll
    for (int z = 0; z < 4; z++) zacc[i][z] = f32x4{0.f, 0.f, 0.f, 0.f};

  stage(0, 0);                     // 6 loads/wave in flight (+4 prologue)
  int cur = 0;
  for (int s = 0; s < 128; s++) {
    if (s < 127) { stage(cur ^ 1, s + 1); WAITV(6); }  // stage-s done, prefetch flying
    else         { WAITV(0); }
    barrier_raw();                 // all waves' stage-s data resident
    const u16* Asb = As[cur];
    const u16* Bsb = Bs[cur];
    #pragma unroll
    for (int ks = 0; ks < 2; ks++) {
      f16x8 a[4];
      #pragma unroll
      for (int mt = 0; mt < 4; mt++)
        a[mt] = *(const f16x8*)(Asb + (ks * 8 + mhalf * 4 + mt) * 512 + lane * 8);
      #pragma unroll
      for (int z = 0; z < 4; z++) {
        int nt = (z >> 1) * 8 + (z & 1) * 4 + ntA;
        f16x8 b = *(const f16x8*)(Bsb + (ks * 16 + nt) * 512 + lane * 8);
        #pragma unroll
        for (int mt = 0; mt < 4; mt++)
          zacc[mt][z] = __builtin_amdgcn_mfma_f32_16x16x32_f16(a[mt], b, zacc[mt][z], 0, 0, 0);
      }
    }
    if ((s & 7) == 7) {
      // epilogue for j-pair jp: bias (LDS) + gelu + contract with fp16 q.
      // Runs while the next stage's loads are still in flight.
      int jp = s >> 3;
      float bgv[4];
      #pragma unroll
      for (int z = 0; z < 4; z++) {
        int nt = (z >> 1) * 8 + (z & 1) * 4 + ntA;
        bgv[z] = bgs[jp * 256 + nt * 16 + l15];
      }
      const int d0 = 4 * jp;
      #pragma unroll
      for (int mt = 0; mt < 4; mt++) {
        #pragma unroll
        for (int r = 0; r < 4; r++) {
          int row = mhalf * 64 + mt * 16 + quad * 4 + r;
          f16x4 qp = *(const f16x4*)(Qs + row * 64 + d0);  // q[row][d0..d0+3]
          float g0 = fast_gelu(zacc[mt][0][r] + bgv[0]);
          float g1 = fast_gelu(zacc[mt][1][r] + bgv[1]);
          float g2 = fast_gelu(zacc[mt][2][r] + bgv[2]);
          float g3 = fast_gelu(zacc[mt][3][r] + bgv[3]);
          qg[mt][r] += (float)qp.x * g0 + (float)qp.y * g1 +
                       (float)qp.z * g2 + (float)qp.w * g3;
        }
      }
      #pragma unroll
      for (int i = 0; i < 4; i++)
        #pragma unroll
        for (int z = 0; z < 4; z++) zacc[i][z] = f32x4{0.f, 0.f, 0.f, 0.f};
    }
    barrier_raw();                 // protect buf[cur] before next iter's stage()
    cur ^= 1;
  }
  // write complete qg as fp16 [B][H][N][D]
  const int eb = ntA * 16;
  #pragma unroll
  for (int mt = 0; mt < 4; mt++) {
    #pragma unroll
    for (int r = 0; r < 4; r++) {
      int t = t0 + mhalf * 64 + mt * 16 + quad * 4 + r;
      int bb = t >> 10, n = t & 1023;
      qg16[(((size_t)(bb * 8 + head) * 1024) + n) * 64 + eb + l15] = f2h_bits(qg[mt][r]);
    }
  }
}

// ---------------------------------------------------------------- flash attention
// Block = (b,h,qtile64), 4 waves x 16 q-rows. qg read directly as fp16,
// K/V double-buffered with counted vmcnt(4) + raw barriers.
__global__ __launch_bounds__(256, 2) void attn_k(
    const u16* __restrict__ qg16, const u16* __restrict__ kb,
    const u16* __restrict__ vTb, float* __restrict__ out) {
  __shared__ __align__(16) u16 Ks[2][8 * 512];
  __shared__ __align__(16) u16 Vs[2][8 * 512];
  __shared__ __align__(16) f16 Ps[4][16 * 72];    // per-wave P, row stride 72
  const int idx = blockIdx.x;
  const int bh = idx & 31;   // b*8+h -> XCD = bh%8
  const int qt = idx >> 5;
  const int b_ = bh >> 3, h = bh & 7;
  const int tid = threadIdx.x;
  const int w = tid >> 6, lane = tid & 63, l15 = lane & 15, quad = lane >> 4;

  const u16* qgB = qg16 + (size_t)bh * 1024 * 64;
  const u16* kB  = kb  + (size_t)bh * 1024 * 64;
  const u16* vB  = vTb + (size_t)bh * 64 * 1024;

  f16x8 aq[2];
  #pragma unroll
  for (int ks = 0; ks < 2; ks++)
    aq[ks] = *(const f16x8*)(qgB + (size_t)(qt * 64 + w * 16 + l15) * 64 + ks * 32 + quad * 8);

  f32x4 o[4];
  #pragma unroll
  for (int i = 0; i < 4; i++) o[i] = f32x4{0.f, 0.f, 0.f, 0.f};
  float m_old[4], l_old[4];
  #pragma unroll
  for (int r = 0; r < 4; r++) { m_old[r] = -1e30f; l_old[r] = 0.f; }

  auto stageKV = [&](int d, int kt) {
    #pragma unroll
    for (int i = 0; i < 2; i++) {
      int cb = w * 2 + i;
      int ks = cb >> 2, nt = cb & 3;
      gll16(kB + (size_t)(kt * 64 + nt * 16 + l15) * 64 + ks * 32 + quad * 8, Ks[d] + cb * 512);
      gll16(vB + (size_t)(nt * 16 + l15) * 1024 + kt * 64 + ks * 32 + quad * 8, Vs[d] + cb * 512);
    }
  };

  stageKV(0, 0);                   // 4 loads/wave in flight
  int cur = 0;
  for (int kt = 0; kt < 16; kt++) {
    if (kt < 15) { stageKV(cur ^ 1, kt + 1); WAITV(4); }
    else         { WAITV(0); }
    barrier_raw();
    f32x4 s[4];
    #pragma unroll
    for (int nt = 0; nt < 4; nt++) s[nt] = f32x4{0.f, 0.f, 0.f, 0.f};
    #pragma unroll
    for (int ks = 0; ks < 2; ks++)
      #pragma unroll
      for (int nt = 0; nt < 4; nt++) {
        f16x8 kf = *(const f16x8*)(Ks[cur] + (ks * 4 + nt) * 512 + lane * 8);
        s[nt] = __builtin_amdgcn_mfma_f32_16x16x32_f16(aq[ks], kf, s[nt], 0, 0, 0);
      }
    float rmax[4];
    #pragma unroll
    for (int r = 0; r < 4; r++)
      rmax[r] = fmaxf(fmaxf(s[0][r], s[1][r]), fmaxf(s[2][r], s[3][r]));
    #pragma unroll
    for (int off = 1; off < 16; off <<= 1)
      #pragma unroll
      for (int r = 0; r < 4; r++)
        rmax[r] = fmaxf(rmax[r], __shfl_xor(rmax[r], off));
    float alpha[4], rsum[4];
    #pragma unroll
    for (int r = 0; r < 4; r++) {
      float mn = fmaxf(m_old[r], rmax[r]);
      alpha[r] = __expf(m_old[r] - mn);
      m_old[r] = mn;
      rsum[r] = 0.f;
    }
    #pragma unroll
    for (int nt = 0; nt < 4; nt++)
      #pragma unroll
      for (int r = 0; r < 4; r++) {
        float p = __expf(s[nt][r] - m_old[r]);
        rsum[r] += p;
        Ps[w][(quad * 4 + r) * 72 + nt * 16 + l15] = (f16)p;
      }
    #pragma unroll
    for (int off = 1; off < 16; off <<= 1)
      #pragma unroll
      for (int r = 0; r < 4; r++)
        rsum[r] += __shfl_xor(rsum[r], off);
    #pragma unroll
    for (int r = 0; r < 4; r++) l_old[r] = l_old[r] * alpha[r] + rsum[r];
    #pragma unroll
    for (int nt = 0; nt < 4; nt++)
      #pragma unroll
      for (int r = 0; r < 4; r++) o[nt][r] *= alpha[r];
    #pragma unroll
    for (int ks = 0; ks < 2; ks++) {
      f16x8 pa = *(const f16x8*)(&Ps[w][l15 * 72 + ks * 32 + quad * 8]);
      #pragma unroll
      for (int nt = 0; nt < 4; nt++) {
        f16x8 vf = *(const f16x8*)(Vs[cur] + (ks * 4 + nt) * 512 + lane * 8);
        o[nt] = __builtin_amdgcn_mfma_f32_16x16x32_f16(pa, vf, o[nt], 0, 0, 0);
      }
    }
    barrier_raw();                 // protect Ks/Vs[cur] before next stageKV
    cur ^= 1;
  }
  #pragma unroll
  for (int r = 0; r < 4; r++) {
    float inv = 1.f / l_old[r];
    int n = qt * 64 + w * 16 + quad * 4 + r;
    #pragma unroll
    for (int nt = 0; nt < 4; nt++)
      out[((size_t)(b_ * 1024 + n)) * 512 + h * 64 + nt * 16 + l15] = o[nt][r] * inv;
  }
}

// ----------------------------------------------------------------------- host
extern "C" void kernel_launch(void* const* d_in, const int* in_sizes, int n_in,
                              void* d_out, int out_size, void* d_ws, size_t ws_size,
                              hipStream_t stream) {
  const float* x  = (const float*)d_in[0];
  const float* Wq = (const float*)d_in[1];
  const float* bq = (const float*)d_in[2];
  const float* Wk = (const float*)d_in[3];
  const float* bk = (const float*)d_in[4];
  const float* Wv = (const float*)d_in[5];
  const float* bv = (const float*)d_in[6];
  const float* Wg = (const float*)d_in[7];
  const float* bg = (const float*)d_in[8];
  float* out = (float*)d_out;

  const size_t NX = (size_t)TOK * EDIM;        // 2M elems
  const size_t NWG = (size_t)GCOLS * EDIM;     // 16.8M elems
  const size_t NW = (size_t)EDIM * EDIM;       // 256K elems

  char* p = (char*)d_ws;
  u16* xf  = (u16*)p; p += NX * 2;             // x fp16
  u16* Wgt = (u16*)p; p += NWG * 2;            // Wg^T fp16 (33.5 MB)
  u16* Wqt = (u16*)p; p += NW * 2;
  u16* Wkt = (u16*)p; p += NW * 2;
  u16* Wvt = (u16*)p; p += NW * 2;
  u16* qh  = (u16*)p; p += NX * 2;             // q fp16 [B][H][N][D]
  u16* kf  = (u16*)p; p += NX * 2;             // k fp16
  u16* vT  = (u16*)p; p += NX * 2;             // v^T fp16
  u16* qg16 = (u16*)p; p += NX * 2;            // qg fp16 [B][H][N][D] (complete)

  hipLaunchKernelGGL(cast_f16_k, dim3(NX / 1024), dim3(256), 0, stream,
                     x, xf, (int)NX);
  hipLaunchKernelGGL(transpose3_f16_k, dim3(EDIM / 64, EDIM / 64, 3), dim3(256), 0, stream,
                     Wq, Wk, Wv, Wqt, Wkt, Wvt);
  hipLaunchKernelGGL(transpose_f16_wide_k, dim3(GCOLS / 64, EDIM / 64), dim3(256), 0, stream,
                     Wg, Wgt, EDIM, GCOLS);
  hipLaunchKernelGGL(qkv_gemm_k, dim3(TOK / 128, EDIM / 128, 3), dim3(256), 0, stream,
                     xf, Wqt, Wkt, Wvt, bq, bk, bv, qh, kf, vT);
  hipLaunchKernelGGL(qg_fused_k, dim3(256), dim3(512), 0, stream,
                     xf, Wgt, bg, qh, qg16);
  hipLaunchKernelGGL(attn_k, dim3(512), dim3(256), 0, stream,
                     qg16, kf, vT, out);
}